// Round 11
// baseline (236.741 us; speedup 1.0000x reference)
//
#include <hip/hip_runtime.h>
#include <cstdint>

// YOLO head: p (8, 4*65, 128, 128) f32 -> out (8, 4*128*128, 65) f32.
// Transpose + cheap elementwise; HBM-bound (~273 MB logical, ~205 MB HBM-visible).
//
// R1: sync loads, 8 blk/CU overlap, depth=1/wave  -> 82.6 us (depth-starved)
// R2/R3: register clauses                          -> ~79 us (null)
// R4: async gload_lds, 65KB deep, 1 blk/CU         -> 83.6 us (phase-serialized)
// R9: + nt stores                                  -> 80.3 us; FETCH UNCHANGED
//     => L3-eviction theory refuted (half the input is evicted by the
//        harness restore BEFORE kernel start; our writes never hurt reads).
// R10 (resubmitted after acquisition timeout): depth x overlap — the untested
//     quadrant. 1-row tile (66.5 KB LDS) -> 2 blocks/CU; async reads keep
//     130 KB/CU queued while the co-resident block's LDS/store phases run.
//     Per-CU read and write streams finally overlap.

namespace {
constexpr int kNA      = 4;
constexpr int kNCH     = 65;
constexpr int kNG      = 128;
constexpr int kThreads = 512;                // 8 waves
constexpr int kTileF   = kNCH * kNG;         // 8320 floats per LDS buffer
constexpr int kLdsBytes= 2 * kTileF * 4;     // 66560 B -> 2 blocks/CU
constexpr int kRow     = kNG * kNG;          // 16384 floats between channels
}

typedef float f32x4 __attribute__((ext_vector_type(4)));

#define AS1 __attribute__((address_space(1)))
#define AS3 __attribute__((address_space(3)))

__device__ __forceinline__ float sigm(float v) { return 1.0f / (1.0f + expf(-v)); }

__global__ __launch_bounds__(kThreads, 4)    // 4 waves/EU = 2 blocks/CU
void yolo_head_kernel(const float* __restrict__ p,
                      const float* __restrict__ anchors,
                      const int* __restrict__ img_dim,
                      float* __restrict__ out)
{
    extern __shared__ float lds[];
    float* in_t  = lds;              // [65][128] channel-major (gload_lds linear)
    float* out_t = lds + kTileF;     // [128][65] output-linear

    const int bid = blockIdx.x;
    const int gy  = bid & (kNG - 1);
    const int ba  = bid >> 7;
    const int a   = ba & (kNA - 1);
    const int b   = ba >> 2;

    const int t    = threadIdx.x;
    const int wv   = t >> 6;                  // wave 0..7
    const int lane = t & 63;

    // ---- phase 1: async global->LDS. Channel pair per instruction:
    // lanes 0-31 read channel 2pi, lanes 32-63 read channel 2pi+1 (per-lane
    // global src); LDS dest wave-uniform, contiguous 1 KB = in_t[2pi..2pi+1][*].
    const float* base = p + ((size_t)(b * (kNA*kNCH) + a * kNCH) * kNG + gy) * kNG;
    #pragma unroll
    for (int i = 0; i < 4; ++i) {
        const int pi = wv * 4 + i;                        // 0..31 (wave-uniform)
        const int c  = 2 * pi + (lane >> 5);              // per-lane channel
        const float* src = base + (size_t)c * kRow + (lane & 31) * 4;
        __builtin_amdgcn_global_load_lds((const AS1 uint32_t*)src,
                                         (AS3 uint32_t*)(in_t + pi * 256),
                                         16, 0, 0);
    }
    if (wv == 0 && lane < 32) {                           // tail channel 64
        const float* src = base + (size_t)64 * kRow + lane * 4;
        __builtin_amdgcn_global_load_lds((const AS1 uint32_t*)src,
                                         (AS3 uint32_t*)(in_t + 64 * kNG),
                                         16, 0, 0);
    }

    const float stride = (float)img_dim[0] / (float)kNG;  // 8.0
    const float aw4 = 4.0f * anchors[2 * a];    // (2w)^2*(anchor/stride)*stride
    const float ah4 = 4.0f * anchors[2 * a + 1];

    __syncthreads();    // vmcnt drain: tile resident

    // ---- phase 2: LDS transpose + transform ----
    // thread -> pixel s = t&127, quad group qg = t>>7; 4 quads per thread.
    // Reads: bank = s mod 32, s consecutive -> 2-way (free). Writes:
    // bank = (s+c) mod 32, s consecutive -> 2-way (free).
    {
        const int s  = t & (kNG - 1);
        const int qg = t >> 7;                            // 0..3
        const float gx  = (float)s;
        const float gyf = (float)gy;
        #pragma unroll
        for (int i = 0; i < 4; ++i) {
            const int q  = qg * 4 + i;                    // 0..15, wave-uniform
            const int c0 = 4 * q;
            float r0 = in_t[(c0 + 0) * kNG + s];
            float r1 = in_t[(c0 + 1) * kNG + s];
            float r2 = in_t[(c0 + 2) * kNG + s];
            float r3 = in_t[(c0 + 3) * kNG + s];
            if (q == 0) {                                 // c = 0..3: x,y,w,h
                r0 = (sigm(r0) + gx) * stride;
                r1 = (sigm(r1) + gyf) * stride;
                float sg = sigm(r2); r2 = sg * sg * aw4;
                sg = sigm(r3);       r3 = sg * sg * ah4;
            } else if (q == 1) {                          // c = 4: objectness
                r0 = sigm(r0);
            }
            float* o = out_t + s * kNCH + c0;
            o[0] = r0; o[1] = r1; o[2] = r2; o[3] = r3;
        }
        if (t < kNG)                                      // tail channel 64
            out_t[t * kNCH + 64] = in_t[64 * kNG + t];
    }

    __syncthreads();

    // ---- phase 3: dense coalesced nt store (out_t is output-linear) ----
    // block base = (ba*16384 + gy*128)*65 floats -> 16B aligned (gy*33280 B).
    f32x4* __restrict__ op = reinterpret_cast<f32x4*>(
        out + (size_t)(ba * (kNG * kNG) + gy * kNG) * kNCH);
    const f32x4* tp = reinterpret_cast<const f32x4*>(out_t);
    #pragma unroll
    for (int i = 0; i < 4; ++i)                           // 4*512 = 2048 of 2080
        __builtin_nontemporal_store(tp[t + i * kThreads], op + t + i * kThreads);
    if (t < 32)                                           // tail 32
        __builtin_nontemporal_store(tp[2048 + t], op + 2048 + t);
}

extern "C" void kernel_launch(void* const* d_in, const int* in_sizes, int n_in,
                              void* d_out, int out_size, void* d_ws, size_t ws_size,
                              hipStream_t stream)
{
    const float* p       = (const float*)d_in[0];
    const float* anchors = (const float*)d_in[1];
    const int*   img_dim = (const int*)d_in[2];
    float* out = (float*)d_out;

    // >64 KB dynamic LDS opt-in; host-side, idempotent, graph-capture safe.
    (void)hipFuncSetAttribute((const void*)yolo_head_kernel,
                              hipFuncAttributeMaxDynamicSharedMemorySize, kLdsBytes);

    const int bs = in_sizes[0] / (kNA * kNCH * kNG * kNG);   // 8
    const int nblocks = bs * kNA * kNG;                      // 4096
    yolo_head_kernel<<<nblocks, kThreads, kLdsBytes, stream>>>(p, anchors, img_dim, out);
}